// Round 15
// baseline (392.108 us; speedup 1.0000x reference)
//
#include <hip/hip_runtime.h>
#include <hip/hip_fp16.h>

// GCN 3-layer: fp16 intermediates, f32 accum, MFMA GEMMs.
// CSR build with ZERO global atomics: 64 dst chunk-histograms (LDS byte-packed)
// -> scan1 converts to per-(chunk,node) exclusive byte prefixes + rp; scatter2
// ranks edges via LDS returning byte-atomic and places them directly.
// Agg: wave/node, uniform masked 16-wide rounds, scalarized csr index loads.
// Math: (x*ns)@W == (x@W)*ns_row; layer-0 folds ns[src] into the gather (fma),
// later layers pre-scale the agg output by ns (relu(x)*s == relu(x*s), s>0).

typedef _Float16 h8 __attribute__((ext_vector_type(8)));
typedef float f32x4 __attribute__((ext_vector_type(4)));

#define HWORDS 25024   // ceil(100000/4), = 391*64 exactly
#define NHS 32         // src histogram chunks
#define NHD 64         // dst histogram chunks (must match scatter2 chunking)

// ---------------- pre: {32 src hist} | {64 dst hist} | {W -> fp16 transposed} ----------
__global__ __launch_bounds__(256) void k_pre(const int* __restrict__ src,
                                             const int* __restrict__ dst, int E,
                                             unsigned* __restrict__ histo_s,
                                             unsigned* __restrict__ histo_d,
                                             const float* __restrict__ W0,
                                             const float* __restrict__ W1,
                                             const float* __restrict__ W2,
                                             __half* __restrict__ Wt0,
                                             __half* __restrict__ Wt1,
                                             __half* __restrict__ Wt2) {
    __shared__ unsigned H[HWORDS];
    const int b = blockIdx.x;
    if (b < NHS + NHD) {
        const bool isS = b < NHS;
        const int c = isS ? b : b - NHS;
        const int NC = isS ? NHS : NHD;
        const int* arr = isS ? src : dst;
        unsigned* outp = (isS ? histo_s : histo_d) + (size_t)c * HWORDS;
        for (int i = threadIdx.x; i < HWORDS; i += 256) H[i] = 0;
        __syncthreads();
        const int perB = ((E + NC - 1) / NC + 3) & ~3;
        const int e0 = c * perB, e1 = min(e0 + perB, E);
        int i = e0 + threadIdx.x * 4;
        for (; i + 3 < e1; i += 1024) {
            int4 s4 = *(const int4*)(arr + i);
            atomicAdd(&H[s4.x >> 2], 1u << ((s4.x & 3) * 8));
            atomicAdd(&H[s4.y >> 2], 1u << ((s4.y & 3) * 8));
            atomicAdd(&H[s4.z >> 2], 1u << ((s4.z & 3) * 8));
            atomicAdd(&H[s4.w >> 2], 1u << ((s4.w & 3) * 8));
        }
        for (; i < e1; ++i) {
            int s = arr[i];
            atomicAdd(&H[s >> 2], 1u << ((s & 3) * 8));
        }
        __syncthreads();
        for (int i2 = threadIdx.x; i2 < HWORDS; i2 += 256) outp[i2] = H[i2];
    } else {
        int j0 = (b - NHS - NHD) * 20480;
        for (int j = j0 + threadIdx.x; j < j0 + 20480; j += 256) {
            if (j < 16384) {
                int nn = j >> 7, k = j & 127;
                Wt0[j] = __float2half(W0[k * 128 + nn]);
            } else if (j < 32768) {
                int i2 = j - 16384;
                int nn = i2 >> 7, k = i2 & 127;
                Wt1[i2] = __float2half(W1[k * 128 + nn]);
            } else if (j < 40960) {
                int i2 = j - 32768;
                int nn = i2 >> 7, k = i2 & 127;
                Wt2[i2] = __float2half(W2[k * 64 + nn]);
            }
        }
    }
}

// ---------------- scan1: dst-prefix transform (in place) + norms + block-local scan ----
__global__ __launch_bounds__(256) void k_scan1(const unsigned* __restrict__ histo_s,
                                               unsigned* __restrict__ histo_d,
                                               int* __restrict__ rp,
                                               int* __restrict__ bsum,
                                               float* __restrict__ ns,
                                               float* __restrict__ nd, int n) {
    __shared__ unsigned di4[64];  // packed deg_i for this block's 256 nodes
    __shared__ unsigned do4[64];  // packed deg_o
    const int tid = threadIdx.x, lane = tid & 63, wid = tid >> 6;
    if (tid < 64) {
        const int w = blockIdx.x * 64 + tid;  // word index (4 nodes); 391*64 == HWORDS
        unsigned run4 = 0;
#pragma unroll
        for (int b = 0; b < NHD; ++b) {
            unsigned c4 = histo_d[(size_t)b * HWORDS + w];
            histo_d[(size_t)b * HWORDS + w] = run4;  // exclusive chunk prefix (bytes)
            run4 += c4;                              // byte-safe: deg < 256
        }
        di4[tid] = run4;
        unsigned s4 = 0;
#pragma unroll
        for (int b = 0; b < NHS; ++b) s4 += histo_s[(size_t)b * HWORDS + w];
        do4[tid] = s4;
    }
    __syncthreads();
    int i = blockIdx.x * 256 + tid;
    int v = 0;
    if (i < n) {
        int sh = (tid & 3) * 8;
        v = (di4[tid >> 2] >> sh) & 255;
        int dgo = (do4[tid >> 2] >> sh) & 255;
        nd[i] = rsqrtf((float)max(v, 1));
        ns[i] = rsqrtf((float)max(dgo, 1));
    }
    int x = v;
#pragma unroll
    for (int off = 1; off < 64; off <<= 1) {
        int t = __shfl_up(x, off, 64);
        if (lane >= off) x += t;
    }
    __shared__ int ws[4];
    if (lane == 63) ws[wid] = x;
    __syncthreads();
    int wo = 0;
    for (int k = 0; k < wid; ++k) wo += ws[k];
    int incl = wo + x;
    if (i < n) rp[i] = incl - v;              // block-local exclusive
    if (tid == 255) bsum[blockIdx.x] = incl;  // block total
}

// scan of block sums
__global__ __launch_bounds__(512) void k_scan2(int* __restrict__ bsum, int nb,
                                               int* __restrict__ rpN) {
    __shared__ int s[512];
    const int tid = threadIdx.x;
    int v = (tid < nb) ? bsum[tid] : 0;
    s[tid] = v;
    __syncthreads();
    for (int off = 1; off < 512; off <<= 1) {
        int t = (tid >= off) ? s[tid - off] : 0;
        __syncthreads();
        s[tid] += t;
        __syncthreads();
    }
    if (tid < nb) bsum[tid] = s[tid] - v;  // exclusive block offsets
    if (tid == nb - 1) *rpN = v;           // last block's local total
}

// ---------------- scatter2: rank via LDS byte-atomic, place edges (no global atomics) --
__global__ __launch_bounds__(256) void k_scatter2(const int* __restrict__ src,
                                                  const int* __restrict__ dst, int E,
                                                  const int* __restrict__ rp,
                                                  const int* __restrict__ bsum,
                                                  const unsigned* __restrict__ pfx_all,
                                                  int* __restrict__ csr) {
    __shared__ unsigned Hd[HWORDS];
    for (int i = threadIdx.x; i < HWORDS; i += 256) Hd[i] = 0;
    __syncthreads();
    const int c = blockIdx.x;
    const int perB = ((E + NHD - 1) / NHD + 3) & ~3;
    const int e0 = c * perB, e1 = min(e0 + perB, E);
    const unsigned* pfx = pfx_all + (size_t)c * HWORDS;
    int i = e0 + threadIdx.x * 4;
    for (; i + 3 < e1; i += 1024) {
        int4 d4 = *(const int4*)(dst + i);
        int4 s4 = *(const int4*)(src + i);
#define PROC(dd, ss)                                                            \
        {                                                                       \
            int sh = ((dd) & 3) * 8;                                            \
            int base = rp[dd] + bsum[(dd) >> 8] +                               \
                       (int)((pfx[(dd) >> 2] >> sh) & 255u);                    \
            unsigned old = atomicAdd(&Hd[(dd) >> 2], 1u << sh);                 \
            csr[base + (int)((old >> sh) & 255u)] = (ss);                       \
        }
        PROC(d4.x, s4.x) PROC(d4.y, s4.y) PROC(d4.z, s4.z) PROC(d4.w, s4.w)
    }
    for (; i < e1; ++i) PROC(dst[i], src[i])
#undef PROC
}

// ---------------- shared GEMM body: C[n,BN](fp16) = A[n,128] @ Wt[BN,128]^T ----------------
// v_mfma_f32_16x16x32_f16; A/B frag = 8 halves at k=8*(lane>>4), row/col=lane&15;
// C/D: col=lane&15, row=(lane>>4)*4+reg (guide m89-verified; round-6 validated).
template <int BN, bool F32A>
__device__ __forceinline__ void gemm_body(const void* __restrict__ Ap,
                                          const __half* __restrict__ Wt,
                                          __half* __restrict__ C, int n, int gb) {
    constexpr int K = 128, BM = 128, LDR = K + 8;  // halves; 272B rows
    __shared__ __half Al[BM * LDR];
    __shared__ __half Bl[BN * LDR];
    const int tid = threadIdx.x;
    const int row0 = gb * BM;
    if (F32A) {
        const float* A = (const float*)Ap;
#pragma unroll
        for (int q = 0; q < 16; ++q) {
            int fi = q * 256 + tid;
            int r = fi >> 5, c = (fi & 31) * 4;
            int gr = row0 + r;
            float4 v = make_float4(0.f, 0.f, 0.f, 0.f);
            if (gr < n) v = *(const float4*)(A + (size_t)gr * K + c);
            __half2 h0 = __floats2half2_rn(v.x, v.y);
            __half2 h1 = __floats2half2_rn(v.z, v.w);
            uint2 pk = make_uint2(*(unsigned*)&h0, *(unsigned*)&h1);
            *(uint2*)&Al[r * LDR + c] = pk;
        }
    } else {
        const __half* A = (const __half*)Ap;
#pragma unroll
        for (int q = 0; q < 8; ++q) {
            int fi = q * 256 + tid;
            int r = fi >> 4, c = (fi & 15) * 8;
            int gr = row0 + r;
            float4 v = make_float4(0.f, 0.f, 0.f, 0.f);
            if (gr < n) v = *(const float4*)(A + (size_t)gr * K + c);
            *(float4*)&Al[r * LDR + c] = v;
        }
    }
#pragma unroll
    for (int q = 0; q < BN / 16; ++q) {
        int fi = q * 256 + tid;
        int r = fi >> 4, c = (fi & 15) * 8;
        *(float4*)&Bl[r * LDR + c] = *(const float4*)(Wt + (size_t)r * K + c);
    }
    __syncthreads();
    const int wid = tid >> 6, lane = tid & 63;
    const int lo = lane & 15, hi = lane >> 4;
    constexpr int NC = BN / 16;
    f32x4 acc[2][NC];
#pragma unroll
    for (int t = 0; t < 2; ++t)
#pragma unroll
        for (int c = 0; c < NC; ++c) acc[t][c] = (f32x4){0.f, 0.f, 0.f, 0.f};
#pragma unroll
    for (int kc = 0; kc < 4; ++kc) {
        h8 aF[2];
#pragma unroll
        for (int t = 0; t < 2; ++t)
            aF[t] = *(const h8*)&Al[(32 * wid + 16 * t + lo) * LDR + 32 * kc + 8 * hi];
#pragma unroll
        for (int c = 0; c < NC; ++c) {
            h8 bF = *(const h8*)&Bl[(16 * c + lo) * LDR + 32 * kc + 8 * hi];
#pragma unroll
            for (int t = 0; t < 2; ++t)
                acc[t][c] = __builtin_amdgcn_mfma_f32_16x16x32_f16(aF[t], bF, acc[t][c], 0, 0, 0);
        }
    }
#pragma unroll
    for (int t = 0; t < 2; ++t) {
#pragma unroll
        for (int j = 0; j < 4; ++j) {
            int gr = row0 + 32 * wid + 16 * t + 4 * hi + j;
            if (gr < n) {
#pragma unroll
                for (int c = 0; c < NC; ++c)
                    C[(size_t)gr * BN + 16 * c + lo] = __float2half(acc[t][c][j]);
            }
        }
    }
}

template <int BN, bool F32A>
__global__ __launch_bounds__(256) void k_gemm(const void* __restrict__ A,
                                              const __half* __restrict__ Wt,
                                              __half* __restrict__ C, int n) {
    gemm_body<BN, F32A>(A, Wt, C, n, blockIdx.x);
}

// ---------------- aggregation D=128: wave/node, half2/lane, masked 16-wide rounds ----
// SSCALE: fold ns[src] per edge (layer 0). Output fp16, pre-scaled by ns[node].
template <bool RELU, bool SSCALE>
__global__ __launch_bounds__(256) void k_agg128h(const __half2* __restrict__ H,  // [N][64]
                                                 const int* __restrict__ rp,
                                                 const int* __restrict__ bsum,
                                                 const int* __restrict__ cs,
                                                 const float* __restrict__ nd,
                                                 const float* __restrict__ ns,
                                                 const float* __restrict__ b,
                                                 __half2* __restrict__ out, int n) {
    const int wid = threadIdx.x >> 6, lane = threadIdx.x & 63;
    const int node = blockIdx.x * 4 + wid;
    if (node >= n) return;
    const int beg = rp[node] + bsum[node >> 8];
    const int end = rp[node + 1] + bsum[(node + 1) >> 8];
    float2 a0 = make_float2(0.f, 0.f), a1 = a0, a2 = a0, a3 = a0;
    float2 a4 = a0, a5 = a0, a6 = a0, a7 = a0;
    for (int e = beg; e < end; e += 16) {
        int s[16];
        float w[16];
#pragma unroll
        for (int j = 0; j < 16; ++j) {
            int idx = e + j;
            int r = (idx < end) ? idx : beg;          // wave-uniform clamp
            r = __builtin_amdgcn_readfirstlane(r);    // scalarize csr index
            s[j] = cs[r];
            w[j] = (idx < end) ? 1.f : 0.f;
        }
        if (SSCALE) {
#pragma unroll
            for (int j = 0; j < 16; ++j) w[j] *= ns[s[j]];
        }
        float2 v[16];
#pragma unroll
        for (int j = 0; j < 16; ++j)
            v[j] = __half22float2(H[(size_t)s[j] * 64 + lane]);
        a0.x = fmaf(v[0].x, w[0], fmaf(v[8].x, w[8], a0.x));
        a0.y = fmaf(v[0].y, w[0], fmaf(v[8].y, w[8], a0.y));
        a1.x = fmaf(v[1].x, w[1], fmaf(v[9].x, w[9], a1.x));
        a1.y = fmaf(v[1].y, w[1], fmaf(v[9].y, w[9], a1.y));
        a2.x = fmaf(v[2].x, w[2], fmaf(v[10].x, w[10], a2.x));
        a2.y = fmaf(v[2].y, w[2], fmaf(v[10].y, w[10], a2.y));
        a3.x = fmaf(v[3].x, w[3], fmaf(v[11].x, w[11], a3.x));
        a3.y = fmaf(v[3].y, w[3], fmaf(v[11].y, w[11], a3.y));
        a4.x = fmaf(v[4].x, w[4], fmaf(v[12].x, w[12], a4.x));
        a4.y = fmaf(v[4].y, w[4], fmaf(v[12].y, w[12], a4.y));
        a5.x = fmaf(v[5].x, w[5], fmaf(v[13].x, w[13], a5.x));
        a5.y = fmaf(v[5].y, w[5], fmaf(v[13].y, w[13], a5.y));
        a6.x = fmaf(v[6].x, w[6], fmaf(v[14].x, w[14], a6.x));
        a6.y = fmaf(v[6].y, w[6], fmaf(v[14].y, w[14], a6.y));
        a7.x = fmaf(v[7].x, w[7], fmaf(v[15].x, w[15], a7.x));
        a7.y = fmaf(v[7].y, w[7], fmaf(v[15].y, w[15], a7.y));
    }
    const float sc = nd[node];
    const float sn = ns[node];
    float2 bb = ((const float2*)b)[lane];
    float ax = ((a0.x + a1.x) + (a2.x + a3.x)) + ((a4.x + a5.x) + (a6.x + a7.x));
    float ay = ((a0.y + a1.y) + (a2.y + a3.y)) + ((a4.y + a5.y) + (a6.y + a7.y));
    float ox = ax * sc + bb.x;
    float oy = ay * sc + bb.y;
    if (RELU) { ox = fmaxf(ox, 0.f); oy = fmaxf(oy, 0.f); }
    ox *= sn; oy *= sn;
    out[(size_t)node * 64 + lane] = __floats2half2_rn(ox, oy);
}

// ---------------- aggregation D=64: wave/node, half/lane, masked 16-wide; f32 out -------
__global__ __launch_bounds__(256) void k_agg64h(const __half* __restrict__ H,  // [N][64]
                                                const int* __restrict__ rp,
                                                const int* __restrict__ bsum,
                                                const int* __restrict__ cs,
                                                const float* __restrict__ nd,
                                                const float* __restrict__ b,
                                                float* __restrict__ out, int n) {
    const int wid = threadIdx.x >> 6, lane = threadIdx.x & 63;
    const int node = blockIdx.x * 4 + wid;
    if (node >= n) return;
    const int beg = rp[node] + bsum[node >> 8];
    const int end = rp[node + 1] + bsum[(node + 1) >> 8];
    float a0 = 0.f, a1 = 0.f, a2 = 0.f, a3 = 0.f;
    float a4 = 0.f, a5 = 0.f, a6 = 0.f, a7 = 0.f;
    for (int e = beg; e < end; e += 16) {
        int s[16];
        float w[16];
#pragma unroll
        for (int j = 0; j < 16; ++j) {
            int idx = e + j;
            int r = (idx < end) ? idx : beg;
            r = __builtin_amdgcn_readfirstlane(r);
            s[j] = cs[r];
            w[j] = (idx < end) ? 1.f : 0.f;
        }
        float v[16];
#pragma unroll
        for (int j = 0; j < 16; ++j)
            v[j] = __half2float(H[(size_t)s[j] * 64 + lane]);
        a0 = fmaf(v[0], w[0], fmaf(v[8], w[8], a0));
        a1 = fmaf(v[1], w[1], fmaf(v[9], w[9], a1));
        a2 = fmaf(v[2], w[2], fmaf(v[10], w[10], a2));
        a3 = fmaf(v[3], w[3], fmaf(v[11], w[11], a3));
        a4 = fmaf(v[4], w[4], fmaf(v[12], w[12], a4));
        a5 = fmaf(v[5], w[5], fmaf(v[13], w[13], a5));
        a6 = fmaf(v[6], w[6], fmaf(v[14], w[14], a6));
        a7 = fmaf(v[7], w[7], fmaf(v[15], w[15], a7));
    }
    float a = ((a0 + a1) + (a2 + a3)) + ((a4 + a5) + (a6 + a7));
    out[(size_t)node * 64 + lane] = a * nd[node] + b[lane];
}

extern "C" void kernel_launch(void* const* d_in, const int* in_sizes, int n_in,
                              void* d_out, int out_size, void* d_ws, size_t ws_size,
                              hipStream_t stream) {
    const float* feat = (const float*)d_in[0];
    const int* ei = (const int*)d_in[1];
    const float* W0 = (const float*)d_in[2];
    const float* b0 = (const float*)d_in[3];
    const float* W1 = (const float*)d_in[4];
    const float* b1 = (const float*)d_in[5];
    const float* W2 = (const float*)d_in[6];
    const float* b2 = (const float*)d_in[7];
    float* out = (float*)d_out;

    const int N = in_sizes[0] / 128;  // 100000
    const int E = in_sizes[1] / 2;    // 1600000
    const int* src = ei;
    const int* dst = ei + E;
    const int NB = (N + 255) / 256;   // 391 scan blocks (= HWORDS/64)

    // workspace layout (16B-aligned chunks)
    char* w = (char*)d_ws;
    float* norm_src = (float*)w; w += (size_t)N * 4;
    float* norm_dst = (float*)w; w += (size_t)N * 4;
    unsigned* histo_s = (unsigned*)w; w += (size_t)NHS * HWORDS * 4;
    unsigned* histo_d = (unsigned*)w; w += (size_t)NHD * HWORDS * 4;
    int* rp    = (int*)w;        w += ((size_t)(N + 1) * 4 + 15) / 16 * 16;
    int* bsum  = (int*)w;        w += 512 * 4;
    int* csr   = (int*)w;        w += (size_t)E * 4;
    __half* Wt0 = (__half*)w;    w += 128 * 128 * 2;
    __half* Wt1 = (__half*)w;    w += 128 * 128 * 2;
    __half* Wt2 = (__half*)w;    w += 128 * 64 * 2;
    __half* Hb = (__half*)w;     w += (size_t)N * 128 * 2;  // GEMM out (gather src)
    __half* Xb = (__half*)w;     w += (size_t)N * 128 * 2;  // agg out / next GEMM in

    const int GB = (N + 127) / 128;   // 782 GEMM blocks
    const int agg_grid = (N + 3) / 4;

    // CSR build, no global atomics
    k_pre<<<NHS + NHD + 2, 256, 0, stream>>>(src, dst, E, histo_s, histo_d,
                                             W0, W1, W2, Wt0, Wt1, Wt2);
    k_scan1<<<NB, 256, 0, stream>>>(histo_s, histo_d, rp, bsum, norm_src, norm_dst, N);
    k_scan2<<<1, 512, 0, stream>>>(bsum, NB, rp + N);
    k_scatter2<<<NHD, 256, 0, stream>>>(src, dst, E, rp, bsum, histo_d, csr);

    // layer 0
    k_gemm<128, true><<<GB, 256, 0, stream>>>(feat, Wt0, Hb, N);
    k_agg128h<true, true><<<agg_grid, 256, 0, stream>>>((const __half2*)Hb, rp, bsum, csr,
                                                        norm_dst, norm_src, b0, (__half2*)Xb, N);
    // layer 1
    k_gemm<128, false><<<GB, 256, 0, stream>>>(Xb, Wt1, Hb, N);
    k_agg128h<true, false><<<agg_grid, 256, 0, stream>>>((const __half2*)Hb, rp, bsum, csr,
                                                         norm_dst, norm_src, b1, (__half2*)Xb, N);
    // layer 2 (BN=64, no relu, f32 out)
    k_gemm<64, false><<<GB, 256, 0, stream>>>(Xb, Wt2, Hb, N);
    k_agg64h<<<agg_grid, 256, 0, stream>>>(Hb, rp, bsum, csr, norm_dst, b2, out, N);
}

// Round 16
// 353.562 us; speedup vs baseline: 1.1090x; 1.1090x over previous
//
#include <hip/hip_runtime.h>
#include <hip/hip_fp16.h>

// GCN 3-layer: fp16 intermediates, f32 accum, MFMA GEMMs.
// CSR build with ZERO global atomics: 256 dst chunk-histograms (LDS byte-packed)
// -> scan1 converts to per-(chunk,node) exclusive byte prefixes + rp; scatter2
// (256 blocks, 1/CU) ranks edges via LDS returning byte-atomic and places them.
// Agg: wave/node, uniform masked 8-wide rounds (round-14 proven), scalarized
// csr index loads.
// Math: (x*ns)@W == (x@W)*ns_row; layer-0 folds ns[src] into the gather (fma),
// later layers pre-scale the agg output by ns (relu(x)*s == relu(x*s), s>0).

typedef _Float16 h8 __attribute__((ext_vector_type(8)));
typedef float f32x4 __attribute__((ext_vector_type(4)));

#define HWORDS 25024   // ceil(100000/4), = 391*64 exactly
#define NHS 32         // src histogram chunks
#define NHD 256        // dst histogram chunks (must match scatter2 chunking)

// ---------------- pre: {32 src hist} | {256 dst hist} | {W -> fp16 transposed} --------
__global__ __launch_bounds__(256) void k_pre(const int* __restrict__ src,
                                             const int* __restrict__ dst, int E,
                                             unsigned* __restrict__ histo_s,
                                             unsigned* __restrict__ histo_d,
                                             const float* __restrict__ W0,
                                             const float* __restrict__ W1,
                                             const float* __restrict__ W2,
                                             __half* __restrict__ Wt0,
                                             __half* __restrict__ Wt1,
                                             __half* __restrict__ Wt2) {
    __shared__ unsigned H[HWORDS];
    const int b = blockIdx.x;
    if (b < NHS + NHD) {
        const bool isS = b < NHS;
        const int c = isS ? b : b - NHS;
        const int NC = isS ? NHS : NHD;
        const int* arr = isS ? src : dst;
        unsigned* outp = (isS ? histo_s : histo_d) + (size_t)c * HWORDS;
        for (int i = threadIdx.x; i < HWORDS; i += 256) H[i] = 0;
        __syncthreads();
        const int perB = ((E + NC - 1) / NC + 3) & ~3;
        const int e0 = min(c * perB, E), e1 = min(e0 + perB, E);
        int i = e0 + threadIdx.x * 4;
        for (; i + 3 < e1; i += 1024) {
            int4 s4 = *(const int4*)(arr + i);
            atomicAdd(&H[s4.x >> 2], 1u << ((s4.x & 3) * 8));
            atomicAdd(&H[s4.y >> 2], 1u << ((s4.y & 3) * 8));
            atomicAdd(&H[s4.z >> 2], 1u << ((s4.z & 3) * 8));
            atomicAdd(&H[s4.w >> 2], 1u << ((s4.w & 3) * 8));
        }
        for (; i < e1; ++i) {
            int s = arr[i];
            atomicAdd(&H[s >> 2], 1u << ((s & 3) * 8));
        }
        __syncthreads();
        for (int i2 = threadIdx.x; i2 < HWORDS; i2 += 256) outp[i2] = H[i2];
    } else {
        int j0 = (b - NHS - NHD) * 20480;
        for (int j = j0 + threadIdx.x; j < j0 + 20480; j += 256) {
            if (j < 16384) {
                int nn = j >> 7, k = j & 127;
                Wt0[j] = __float2half(W0[k * 128 + nn]);
            } else if (j < 32768) {
                int i2 = j - 16384;
                int nn = i2 >> 7, k = i2 & 127;
                Wt1[i2] = __float2half(W1[k * 128 + nn]);
            } else if (j < 40960) {
                int i2 = j - 32768;
                int nn = i2 >> 7, k = i2 & 127;
                Wt2[i2] = __float2half(W2[k * 64 + nn]);
            }
        }
    }
}

// ---------------- scan1: dst-prefix transform (in place) + norms + block-local scan ----
__global__ __launch_bounds__(256) void k_scan1(const unsigned* __restrict__ histo_s,
                                               unsigned* __restrict__ histo_d,
                                               int* __restrict__ rp,
                                               int* __restrict__ bsum,
                                               float* __restrict__ ns,
                                               float* __restrict__ nd, int n) {
    __shared__ unsigned di4[64];  // packed deg_i for this block's 256 nodes
    __shared__ unsigned do4[64];  // packed deg_o
    const int tid = threadIdx.x, lane = tid & 63, wid = tid >> 6;
    if (tid < 64) {
        const int w = blockIdx.x * 64 + tid;  // word index (4 nodes); 391*64 == HWORDS
        unsigned run4 = 0;
#pragma unroll 8
        for (int b = 0; b < NHD; ++b) {
            unsigned c4 = histo_d[(size_t)b * HWORDS + w];
            histo_d[(size_t)b * HWORDS + w] = run4;  // exclusive chunk prefix (bytes)
            run4 += c4;                              // byte-safe: deg < 256
        }
        di4[tid] = run4;
        unsigned s4 = 0;
#pragma unroll 8
        for (int b = 0; b < NHS; ++b) s4 += histo_s[(size_t)b * HWORDS + w];
        do4[tid] = s4;
    }
    __syncthreads();
    int i = blockIdx.x * 256 + tid;
    int v = 0;
    if (i < n) {
        int sh = (tid & 3) * 8;
        v = (di4[tid >> 2] >> sh) & 255;
        int dgo = (do4[tid >> 2] >> sh) & 255;
        nd[i] = rsqrtf((float)max(v, 1));
        ns[i] = rsqrtf((float)max(dgo, 1));
    }
    int x = v;
#pragma unroll
    for (int off = 1; off < 64; off <<= 1) {
        int t = __shfl_up(x, off, 64);
        if (lane >= off) x += t;
    }
    __shared__ int ws[4];
    if (lane == 63) ws[wid] = x;
    __syncthreads();
    int wo = 0;
    for (int k = 0; k < wid; ++k) wo += ws[k];
    int incl = wo + x;
    if (i < n) rp[i] = incl - v;              // block-local exclusive
    if (tid == 255) bsum[blockIdx.x] = incl;  // block total
}

// scan of block sums
__global__ __launch_bounds__(512) void k_scan2(int* __restrict__ bsum, int nb,
                                               int* __restrict__ rpN) {
    __shared__ int s[512];
    const int tid = threadIdx.x;
    int v = (tid < nb) ? bsum[tid] : 0;
    s[tid] = v;
    __syncthreads();
    for (int off = 1; off < 512; off <<= 1) {
        int t = (tid >= off) ? s[tid - off] : 0;
        __syncthreads();
        s[tid] += t;
        __syncthreads();
    }
    if (tid < nb) bsum[tid] = s[tid] - v;  // exclusive block offsets
    if (tid == nb - 1) *rpN = v;           // last block's local total
}

// ---------------- scatter2: rank via LDS byte-atomic, place edges (no global atomics) --
__global__ __launch_bounds__(256) void k_scatter2(const int* __restrict__ src,
                                                  const int* __restrict__ dst, int E,
                                                  const int* __restrict__ rp,
                                                  const int* __restrict__ bsum,
                                                  const unsigned* __restrict__ pfx_all,
                                                  int* __restrict__ csr) {
    __shared__ unsigned Hd[HWORDS];
    for (int i = threadIdx.x; i < HWORDS; i += 256) Hd[i] = 0;
    __syncthreads();
    const int c = blockIdx.x;
    const int perB = ((E + NHD - 1) / NHD + 3) & ~3;
    const int e0 = min(c * perB, E), e1 = min(e0 + perB, E);
    const unsigned* pfx = pfx_all + (size_t)c * HWORDS;
    int i = e0 + threadIdx.x * 4;
    for (; i + 3 < e1; i += 1024) {
        int4 d4 = *(const int4*)(dst + i);
        int4 s4 = *(const int4*)(src + i);
#define PROC(dd, ss)                                                            \
        {                                                                       \
            int sh = ((dd) & 3) * 8;                                            \
            int base = rp[dd] + bsum[(dd) >> 8] +                               \
                       (int)((pfx[(dd) >> 2] >> sh) & 255u);                    \
            unsigned old = atomicAdd(&Hd[(dd) >> 2], 1u << sh);                 \
            csr[base + (int)((old >> sh) & 255u)] = (ss);                       \
        }
        PROC(d4.x, s4.x) PROC(d4.y, s4.y) PROC(d4.z, s4.z) PROC(d4.w, s4.w)
    }
    for (; i < e1; ++i) PROC(dst[i], src[i])
#undef PROC
}

// ---------------- shared GEMM body: C[n,BN](fp16) = A[n,128] @ Wt[BN,128]^T ----------------
// v_mfma_f32_16x16x32_f16; A/B frag = 8 halves at k=8*(lane>>4), row/col=lane&15;
// C/D: col=lane&15, row=(lane>>4)*4+reg (guide m89-verified; round-6 validated).
template <int BN, bool F32A>
__device__ __forceinline__ void gemm_body(const void* __restrict__ Ap,
                                          const __half* __restrict__ Wt,
                                          __half* __restrict__ C, int n, int gb) {
    constexpr int K = 128, BM = 128, LDR = K + 8;  // halves; 272B rows
    __shared__ __half Al[BM * LDR];
    __shared__ __half Bl[BN * LDR];
    const int tid = threadIdx.x;
    const int row0 = gb * BM;
    if (F32A) {
        const float* A = (const float*)Ap;
#pragma unroll
        for (int q = 0; q < 16; ++q) {
            int fi = q * 256 + tid;
            int r = fi >> 5, c = (fi & 31) * 4;
            int gr = row0 + r;
            float4 v = make_float4(0.f, 0.f, 0.f, 0.f);
            if (gr < n) v = *(const float4*)(A + (size_t)gr * K + c);
            __half2 h0 = __floats2half2_rn(v.x, v.y);
            __half2 h1 = __floats2half2_rn(v.z, v.w);
            uint2 pk = make_uint2(*(unsigned*)&h0, *(unsigned*)&h1);
            *(uint2*)&Al[r * LDR + c] = pk;
        }
    } else {
        const __half* A = (const __half*)Ap;
#pragma unroll
        for (int q = 0; q < 8; ++q) {
            int fi = q * 256 + tid;
            int r = fi >> 4, c = (fi & 15) * 8;
            int gr = row0 + r;
            float4 v = make_float4(0.f, 0.f, 0.f, 0.f);
            if (gr < n) v = *(const float4*)(A + (size_t)gr * K + c);
            *(float4*)&Al[r * LDR + c] = v;
        }
    }
#pragma unroll
    for (int q = 0; q < BN / 16; ++q) {
        int fi = q * 256 + tid;
        int r = fi >> 4, c = (fi & 15) * 8;
        *(float4*)&Bl[r * LDR + c] = *(const float4*)(Wt + (size_t)r * K + c);
    }
    __syncthreads();
    const int wid = tid >> 6, lane = tid & 63;
    const int lo = lane & 15, hi = lane >> 4;
    constexpr int NC = BN / 16;
    f32x4 acc[2][NC];
#pragma unroll
    for (int t = 0; t < 2; ++t)
#pragma unroll
        for (int c = 0; c < NC; ++c) acc[t][c] = (f32x4){0.f, 0.f, 0.f, 0.f};
#pragma unroll
    for (int kc = 0; kc < 4; ++kc) {
        h8 aF[2];
#pragma unroll
        for (int t = 0; t < 2; ++t)
            aF[t] = *(const h8*)&Al[(32 * wid + 16 * t + lo) * LDR + 32 * kc + 8 * hi];
#pragma unroll
        for (int c = 0; c < NC; ++c) {
            h8 bF = *(const h8*)&Bl[(16 * c + lo) * LDR + 32 * kc + 8 * hi];
#pragma unroll
            for (int t = 0; t < 2; ++t)
                acc[t][c] = __builtin_amdgcn_mfma_f32_16x16x32_f16(aF[t], bF, acc[t][c], 0, 0, 0);
        }
    }
#pragma unroll
    for (int t = 0; t < 2; ++t) {
#pragma unroll
        for (int j = 0; j < 4; ++j) {
            int gr = row0 + 32 * wid + 16 * t + 4 * hi + j;
            if (gr < n) {
#pragma unroll
                for (int c = 0; c < NC; ++c)
                    C[(size_t)gr * BN + 16 * c + lo] = __float2half(acc[t][c][j]);
            }
        }
    }
}

template <int BN, bool F32A>
__global__ __launch_bounds__(256) void k_gemm(const void* __restrict__ A,
                                              const __half* __restrict__ Wt,
                                              __half* __restrict__ C, int n) {
    gemm_body<BN, F32A>(A, Wt, C, n, blockIdx.x);
}

// ---------------- aggregation D=128: wave/node, half2/lane, masked 8-wide rounds ----
// SSCALE: fold ns[src] per edge (layer 0). Output fp16, pre-scaled by ns[node].
// Index clamp (idx<end ? idx : beg) is always a valid read -> no tail ladder;
// out-of-range contributions are zeroed via the fma weight. (round-14 proven)
template <bool RELU, bool SSCALE>
__global__ __launch_bounds__(256) void k_agg128h(const __half2* __restrict__ H,  // [N][64]
                                                 const int* __restrict__ rp,
                                                 const int* __restrict__ bsum,
                                                 const int* __restrict__ cs,
                                                 const float* __restrict__ nd,
                                                 const float* __restrict__ ns,
                                                 const float* __restrict__ b,
                                                 __half2* __restrict__ out, int n) {
    const int wid = threadIdx.x >> 6, lane = threadIdx.x & 63;
    const int node = blockIdx.x * 4 + wid;
    if (node >= n) return;
    const int beg = rp[node] + bsum[node >> 8];
    const int end = rp[node + 1] + bsum[(node + 1) >> 8];
    float2 a0 = make_float2(0.f, 0.f), a1 = a0, a2 = a0, a3 = a0;
    float2 a4 = a0, a5 = a0, a6 = a0, a7 = a0;
    for (int e = beg; e < end; e += 8) {
        int s[8];
        float w[8];
#pragma unroll
        for (int j = 0; j < 8; ++j) {
            int idx = e + j;
            int r = (idx < end) ? idx : beg;                  // wave-uniform clamp
            r = __builtin_amdgcn_readfirstlane(r);            // scalarize csr index
            s[j] = cs[r];
            w[j] = (idx < end) ? 1.f : 0.f;
        }
        if (SSCALE) {
#pragma unroll
            for (int j = 0; j < 8; ++j) w[j] *= ns[s[j]];
        }
        float2 v0 = __half22float2(H[(size_t)s[0] * 64 + lane]);
        float2 v1 = __half22float2(H[(size_t)s[1] * 64 + lane]);
        float2 v2 = __half22float2(H[(size_t)s[2] * 64 + lane]);
        float2 v3 = __half22float2(H[(size_t)s[3] * 64 + lane]);
        float2 v4 = __half22float2(H[(size_t)s[4] * 64 + lane]);
        float2 v5 = __half22float2(H[(size_t)s[5] * 64 + lane]);
        float2 v6 = __half22float2(H[(size_t)s[6] * 64 + lane]);
        float2 v7 = __half22float2(H[(size_t)s[7] * 64 + lane]);
        a0.x = fmaf(v0.x, w[0], a0.x); a0.y = fmaf(v0.y, w[0], a0.y);
        a1.x = fmaf(v1.x, w[1], a1.x); a1.y = fmaf(v1.y, w[1], a1.y);
        a2.x = fmaf(v2.x, w[2], a2.x); a2.y = fmaf(v2.y, w[2], a2.y);
        a3.x = fmaf(v3.x, w[3], a3.x); a3.y = fmaf(v3.y, w[3], a3.y);
        a4.x = fmaf(v4.x, w[4], a4.x); a4.y = fmaf(v4.y, w[4], a4.y);
        a5.x = fmaf(v5.x, w[5], a5.x); a5.y = fmaf(v5.y, w[5], a5.y);
        a6.x = fmaf(v6.x, w[6], a6.x); a6.y = fmaf(v6.y, w[6], a6.y);
        a7.x = fmaf(v7.x, w[7], a7.x); a7.y = fmaf(v7.y, w[7], a7.y);
    }
    const float sc = nd[node];
    const float sn = ns[node];
    float2 bb = ((const float2*)b)[lane];
    float ax = ((a0.x + a1.x) + (a2.x + a3.x)) + ((a4.x + a5.x) + (a6.x + a7.x));
    float ay = ((a0.y + a1.y) + (a2.y + a3.y)) + ((a4.y + a5.y) + (a6.y + a7.y));
    float ox = ax * sc + bb.x;
    float oy = ay * sc + bb.y;
    if (RELU) { ox = fmaxf(ox, 0.f); oy = fmaxf(oy, 0.f); }
    ox *= sn; oy *= sn;
    out[(size_t)node * 64 + lane] = __floats2half2_rn(ox, oy);
}

// ---------------- aggregation D=64: wave/node, half/lane, masked 8-wide; f32 out --------
__global__ __launch_bounds__(256) void k_agg64h(const __half* __restrict__ H,  // [N][64]
                                                const int* __restrict__ rp,
                                                const int* __restrict__ bsum,
                                                const int* __restrict__ cs,
                                                const float* __restrict__ nd,
                                                const float* __restrict__ b,
                                                float* __restrict__ out, int n) {
    const int wid = threadIdx.x >> 6, lane = threadIdx.x & 63;
    const int node = blockIdx.x * 4 + wid;
    if (node >= n) return;
    const int beg = rp[node] + bsum[node >> 8];
    const int end = rp[node + 1] + bsum[(node + 1) >> 8];
    float a0 = 0.f, a1 = 0.f, a2 = 0.f, a3 = 0.f;
    float a4 = 0.f, a5 = 0.f, a6 = 0.f, a7 = 0.f;
    for (int e = beg; e < end; e += 8) {
        int s[8];
        float w[8];
#pragma unroll
        for (int j = 0; j < 8; ++j) {
            int idx = e + j;
            int r = (idx < end) ? idx : beg;
            r = __builtin_amdgcn_readfirstlane(r);
            s[j] = cs[r];
            w[j] = (idx < end) ? 1.f : 0.f;
        }
        a0 = fmaf(__half2float(H[(size_t)s[0] * 64 + lane]), w[0], a0);
        a1 = fmaf(__half2float(H[(size_t)s[1] * 64 + lane]), w[1], a1);
        a2 = fmaf(__half2float(H[(size_t)s[2] * 64 + lane]), w[2], a2);
        a3 = fmaf(__half2float(H[(size_t)s[3] * 64 + lane]), w[3], a3);
        a4 = fmaf(__half2float(H[(size_t)s[4] * 64 + lane]), w[4], a4);
        a5 = fmaf(__half2float(H[(size_t)s[5] * 64 + lane]), w[5], a5);
        a6 = fmaf(__half2float(H[(size_t)s[6] * 64 + lane]), w[6], a6);
        a7 = fmaf(__half2float(H[(size_t)s[7] * 64 + lane]), w[7], a7);
    }
    float a = ((a0 + a1) + (a2 + a3)) + ((a4 + a5) + (a6 + a7));
    out[(size_t)node * 64 + lane] = a * nd[node] + b[lane];
}

extern "C" void kernel_launch(void* const* d_in, const int* in_sizes, int n_in,
                              void* d_out, int out_size, void* d_ws, size_t ws_size,
                              hipStream_t stream) {
    const float* feat = (const float*)d_in[0];
    const int* ei = (const int*)d_in[1];
    const float* W0 = (const float*)d_in[2];
    const float* b0 = (const float*)d_in[3];
    const float* W1 = (const float*)d_in[4];
    const float* b1 = (const float*)d_in[5];
    const float* W2 = (const float*)d_in[6];
    const float* b2 = (const float*)d_in[7];
    float* out = (float*)d_out;

    const int N = in_sizes[0] / 128;  // 100000
    const int E = in_sizes[1] / 2;    // 1600000
    const int* src = ei;
    const int* dst = ei + E;
    const int NB = (N + 255) / 256;   // 391 scan blocks (= HWORDS/64)

    // workspace layout (16B-aligned chunks)
    char* w = (char*)d_ws;
    float* norm_src = (float*)w; w += (size_t)N * 4;
    float* norm_dst = (float*)w; w += (size_t)N * 4;
    unsigned* histo_s = (unsigned*)w; w += (size_t)NHS * HWORDS * 4;
    unsigned* histo_d = (unsigned*)w; w += (size_t)NHD * HWORDS * 4;
    int* rp    = (int*)w;        w += ((size_t)(N + 1) * 4 + 15) / 16 * 16;
    int* bsum  = (int*)w;        w += 512 * 4;
    int* csr   = (int*)w;        w += (size_t)E * 4;
    __half* Wt0 = (__half*)w;    w += 128 * 128 * 2;
    __half* Wt1 = (__half*)w;    w += 128 * 128 * 2;
    __half* Wt2 = (__half*)w;    w += 128 * 64 * 2;
    __half* Hb = (__half*)w;     w += (size_t)N * 128 * 2;  // GEMM out (gather src)
    __half* Xb = (__half*)w;     w += (size_t)N * 128 * 2;  // agg out / next GEMM in

    const int GB = (N + 127) / 128;   // 782 GEMM blocks
    const int agg_grid = (N + 3) / 4;

    // CSR build, no global atomics
    k_pre<<<NHS + NHD + 2, 256, 0, stream>>>(src, dst, E, histo_s, histo_d,
                                             W0, W1, W2, Wt0, Wt1, Wt2);
    k_scan1<<<NB, 256, 0, stream>>>(histo_s, histo_d, rp, bsum, norm_src, norm_dst, N);
    k_scan2<<<1, 512, 0, stream>>>(bsum, NB, rp + N);
    k_scatter2<<<NHD, 256, 0, stream>>>(src, dst, E, rp, bsum, histo_d, csr);

    // layer 0
    k_gemm<128, true><<<GB, 256, 0, stream>>>(feat, Wt0, Hb, N);
    k_agg128h<true, true><<<agg_grid, 256, 0, stream>>>((const __half2*)Hb, rp, bsum, csr,
                                                        norm_dst, norm_src, b0, (__half2*)Xb, N);
    // layer 1
    k_gemm<128, false><<<GB, 256, 0, stream>>>(Xb, Wt1, Hb, N);
    k_agg128h<true, false><<<agg_grid, 256, 0, stream>>>((const __half2*)Hb, rp, bsum, csr,
                                                         norm_dst, norm_src, b1, (__half2*)Xb, N);
    // layer 2 (BN=64, no relu, f32 out)
    k_gemm<64, false><<<GB, 256, 0, stream>>>(Xb, Wt2, Hb, N);
    k_agg64h<<<agg_grid, 256, 0, stream>>>(Hb, rp, bsum, csr, norm_dst, b2, out, N);
}